// Round 1
// baseline (47.200 us; speedup 1.0000x reference)
//
#include <hip/hip_runtime.h>

// Problem constants (fixed by reference): B=16, H=W=1024.
#define NPIX (16u * 1024u * 1024u)   // B*H*W = 16,777,216 pixels
#define NQUADS (NPIX / 4u)           // 4 pixels per loop iteration
#define NBLOCKS 2048
#define NTHREADS 256

// Stage 1: per-block partial sum of squared errors over both channels.
// predicted_images is [B,H,W,2] interleaved: pixel i -> (char, aff) at pred[2i], pred[2i+1].
// As float4: pred4[2q] = (c[4q], a[4q], c[4q+1], a[4q+1]), pred4[2q+1] = (c[4q+2], a[4q+2], c[4q+3], a[4q+3]).
// cgt4[q] = char_gt[4q..4q+3], agt4[q] = aff_gt[4q..4q+3].
__global__ __launch_bounds__(NTHREADS) void ohem_partial_kernel(
    const float4* __restrict__ pred4,
    const float4* __restrict__ cgt4,
    const float4* __restrict__ agt4,
    float* __restrict__ partials) {
  const unsigned tid = blockIdx.x * NTHREADS + threadIdx.x;
  const unsigned stride = gridDim.x * NTHREADS;

  float acc = 0.0f;
  for (unsigned q = tid; q < NQUADS; q += stride) {
    float4 p01 = pred4[2u * q];
    float4 p23 = pred4[2u * q + 1u];
    float4 c = cgt4[q];
    float4 a = agt4[q];
    float d;
    d = p01.x - c.x; acc = fmaf(d, d, acc);
    d = p01.z - c.y; acc = fmaf(d, d, acc);
    d = p23.x - c.z; acc = fmaf(d, d, acc);
    d = p23.z - c.w; acc = fmaf(d, d, acc);
    d = p01.y - a.x; acc = fmaf(d, d, acc);
    d = p01.w - a.y; acc = fmaf(d, d, acc);
    d = p23.y - a.z; acc = fmaf(d, d, acc);
    d = p23.w - a.w; acc = fmaf(d, d, acc);
  }

  // Wave-64 butterfly reduce.
  #pragma unroll
  for (int off = 32; off > 0; off >>= 1) acc += __shfl_down(acc, off, 64);

  __shared__ float smem[NTHREADS / 64];
  const int wave = threadIdx.x >> 6;
  if ((threadIdx.x & 63) == 0) smem[wave] = acc;
  __syncthreads();
  if (threadIdx.x == 0) {
    float t = 0.0f;
    #pragma unroll
    for (int w = 0; w < NTHREADS / 64; ++w) t += smem[w];
    partials[blockIdx.x] = t;
  }
}

// Stage 2: deterministic final reduce (one block), double accumulation.
__global__ __launch_bounds__(NTHREADS) void ohem_final_kernel(
    const float* __restrict__ partials, float* __restrict__ out) {
  double acc = 0.0;
  for (int i = threadIdx.x; i < NBLOCKS; i += NTHREADS) acc += (double)partials[i];

  #pragma unroll
  for (int off = 32; off > 0; off >>= 1) acc += __shfl_down(acc, off, 64);

  __shared__ double smem[NTHREADS / 64];
  const int wave = threadIdx.x >> 6;
  if ((threadIdx.x & 63) == 0) smem[wave] = acc;
  __syncthreads();
  if (threadIdx.x == 0) {
    double t = 0.0;
    #pragma unroll
    for (int w = 0; w < NTHREADS / 64; ++w) t += smem[w];
    // loss = sum_sq_char/N + sum_sq_aff/N = total_sum_sq / N
    out[0] = (float)(t / (double)NPIX);
  }
}

extern "C" void kernel_launch(void* const* d_in, const int* in_sizes, int n_in,
                              void* d_out, int out_size, void* d_ws, size_t ws_size,
                              hipStream_t stream) {
  const float4* pred4 = (const float4*)d_in[0];  // [B,H,W,2] fp32
  const float4* cgt4 = (const float4*)d_in[1];   // [B,H,W] fp32
  const float4* agt4 = (const float4*)d_in[2];   // [B,H,W] fp32
  float* out = (float*)d_out;
  float* partials = (float*)d_ws;  // NBLOCKS floats = 8 KB

  ohem_partial_kernel<<<NBLOCKS, NTHREADS, 0, stream>>>(pred4, cgt4, agt4, partials);
  ohem_final_kernel<<<1, NTHREADS, 0, stream>>>(partials, out);
}